// Round 21
// baseline (644.087 us; speedup 1.0000x reference)
//
#include <hip/hip_runtime.h>

// ---------------------------------------------------------------------------
// SimplifiedMambaModel on MI355X (gfx950)
// B=32 T=2048 D=512 S=64 L=4 V=32000 C=2
//  - LN folded into weights (gate = s_r*(x@Wg'^T) - m_r*s_r*P + Q); GEMMs
//    consume RAW bf16 x; no xn tensor
//  - residual ping-pong x <-> x2 (bf16)
//  - gateop: 2-barrier BK=128 + XCD remap, 512 threads (r17-r20 proven, 68us)
//  - ln_u: 512 threads, 32 rows/block (r18 proven)
//  - scan: 8-step chunks (8192 waves, 32 blocks/CU), 16-step warmup
// ---------------------------------------------------------------------------

#define DEV __device__ __forceinline__

typedef __attribute__((ext_vector_type(8))) short short8v;   // 8 x bf16
typedef __attribute__((ext_vector_type(4))) float f32x4;     // MFMA C/D frag

static constexpr int Bn = 32, Tn = 2048, Dn = 512, Sn = 64, Lk = 4;
static constexpr int Mrows = Bn * Tn;  // 65536

DEV unsigned short f2bf(float f) {          // RNE float->bf16
  unsigned u = __float_as_uint(f);
  u += 0x7fffu + ((u >> 16) & 1u);
  return (unsigned short)(u >> 16);
}
DEV float bf2f(unsigned short h) { return __uint_as_float(((unsigned)h) << 16); }

DEV void g2lds16(const void* g, void* l) {
  __builtin_amdgcn_global_load_lds(
      (const __attribute__((address_space(1))) void*)g,
      (__attribute__((address_space(3))) void*)l, 16, 0, 0);
}

// Stage a [ROWS x 64-bf16] tile (128B LDS rows) with T2 XOR swizzle.
// Readers XOR full ushort col index with ((row&7)<<3).
template <int THREADS, int ROWS>
DEV void stage_sw(const char* gbase, size_t rowStride, size_t kOff, char* lds, int tid) {
#pragma unroll
  for (int r = 0; r < ROWS * 128 / (THREADS * 16); ++r) {
    int o = r * THREADS * 16 + tid * 16;
    int row = o >> 7, kb = o & 127;
    g2lds16(gbase + (size_t)row * rowStride + kOff + (size_t)(kb ^ ((row & 7) << 4)),
            lds + o);
  }
}

// Stage a [128 x 128-bf16] tile (256B LDS rows) with the same per-128B-window
// XOR swizzle; global rows are 1024B (x / WgP).
template <int THREADS>
DEV void stage_sw128(const char* gbase, size_t kOff, char* lds, int tid) {
#pragma unroll
  for (int r = 0; r < 32768 / (THREADS * 16); ++r) {
    int o = r * THREADS * 16 + tid * 16;
    int row = o >> 8, kb = o & 255;
    g2lds16(gbase + (size_t)row * 1024 + kOff + (size_t)(kb ^ ((row & 7) << 4)),
            lds + o);
  }
}

// ---------------------------------------------------------------------------
// Weight prep: folded weights + column sums.
// ---------------------------------------------------------------------------
__global__ __launch_bounds__(256) void prep_kernel(
    const float* __restrict__ Wg, const float* __restrict__ Wop,
    const float* __restrict__ Wsp, const float* __restrict__ Wip,
    const float* __restrict__ bsp, const float* __restrict__ bip,
    const float* __restrict__ lnw, const float* __restrict__ lnb,
    unsigned short* __restrict__ WgP, unsigned short* __restrict__ WuP,
    unsigned short* __restrict__ WopB,
    float* __restrict__ P, float* __restrict__ Q,
    float* __restrict__ Pu, float* __restrict__ Qu, float* __restrict__ bu) {
  const int blk = blockIdx.x, tid = threadIdx.x, lane = tid & 63, w = tid >> 6;
  if (blk < 512) {
    int idx = blk * 4 + w;                  // = l*512 + col
    int l = idx >> 9;
    const float* src = Wg + (size_t)idx * 512;
    const float* gw = lnw + (size_t)l * 512;
    const float* gb = lnb + (size_t)l * 512;
    unsigned short* dst = WgP + (size_t)idx * 512;
    float p = 0.f, q = 0.f;
#pragma unroll
    for (int e = 0; e < 8; ++e) {
      int k = lane * 8 + e;
      float wv = src[k];
      unsigned short hb = f2bf(gw[k] * wv);
      dst[k] = hb;
      p += bf2f(hb);
      q += gb[k] * wv;
    }
#pragma unroll
    for (int m = 32; m >= 1; m >>= 1) { p += __shfl_xor(p, m); q += __shfl_xor(q, m); }
    if (lane == 0) { P[idx] = p; Q[idx] = q; }
  } else if (blk < 576) {
    int idx = (blk - 512) * 4 + w;          // = l*64 + col
    int l = idx >> 6;
    const float* s1 = Wsp + (size_t)idx * 512;
    const float* s2 = Wip + (size_t)idx * 512;
    const float* gw = lnw + (size_t)l * 512;
    const float* gb = lnb + (size_t)l * 512;
    unsigned short* dst = WuP + (size_t)idx * 512;
    float p = 0.f, q = 0.f;
#pragma unroll
    for (int e = 0; e < 8; ++e) {
      int k = lane * 8 + e;
      float wv = s1[k] + s2[k];
      unsigned short hb = f2bf(gw[k] * wv);
      dst[k] = hb;
      p += bf2f(hb);
      q += gb[k] * wv;
    }
#pragma unroll
    for (int m = 32; m >= 1; m >>= 1) { p += __shfl_xor(p, m); q += __shfl_xor(q, m); }
    if (lane == 0) { Pu[idx] = p; Qu[idx] = q; bu[idx] = bsp[idx] + bip[idx]; }
  } else {
    int i = (blk - 576) * 256 + tid;
    if (i < Lk * Dn * Sn) WopB[i] = f2bf(Wop[i]);
  }
}

// ---------------------------------------------------------------------------
// Fused (embed +) LN-stats + u-projection.  32 rows/block, 512 threads
// (8 waves: 2 row-groups x 4 col-tiles).  As 32KB + Bs 32KB = 64KB ->
// 2 blocks/CU = 16 waves/CU.   u = s*(x@WuP^T) - m*s*Pu + Qu + bu
// ---------------------------------------------------------------------------
template <int EMB>
__global__ __launch_bounds__(512) void ln_u_kernel(
    const unsigned short* __restrict__ x,    // [Mc,512] bf16 (EMB=0)
    const int* __restrict__ tok,             // EMB=1
    const float* __restrict__ emb,           // EMB=1
    unsigned short* __restrict__ xw,         // EMB=1: write x
    const unsigned short* __restrict__ WuP,  // [64,512] layer slice
    const float* __restrict__ Pu, const float* __restrict__ Qu,
    const float* __restrict__ bu,
    unsigned short* __restrict__ u,          // [Mc,64] bf16
    float* __restrict__ meanA, float* __restrict__ rstdA) {
  __shared__ __align__(16) unsigned short As[32 * 512];   // raw x, swizzled
  __shared__ __align__(16) unsigned short Bs[64 * 256];   // Wu k-phase, swz
  __shared__ float mS[32], rS[32];
  const int tid = threadIdx.x, lane = tid & 63, w = tid >> 6;
  const int row0 = blockIdx.x * 32;

#pragma unroll
  for (int i = 0; i < 4; ++i) {
    int row = w * 4 + i;
    size_t grow = (size_t)(row0 + row);
    short8v v;
    if (EMB) {
      int t = tok[grow];
      const float4* src = (const float4*)(emb + (size_t)t * Dn + lane * 8);
      float4 a = src[0], b = src[1];
      const float scale = 22.627416997969522f;   // sqrt(512)
      v[0] = (short)f2bf(a.x * scale); v[1] = (short)f2bf(a.y * scale);
      v[2] = (short)f2bf(a.z * scale); v[3] = (short)f2bf(a.w * scale);
      v[4] = (short)f2bf(b.x * scale); v[5] = (short)f2bf(b.y * scale);
      v[6] = (short)f2bf(b.z * scale); v[7] = (short)f2bf(b.w * scale);
      *(short8v*)(xw + grow * 512 + lane * 8) = v;
    } else {
      v = *(const short8v*)(x + grow * 512 + lane * 8);
    }
    float f0 = bf2f((unsigned short)v[0]), f1 = bf2f((unsigned short)v[1]);
    float f2 = bf2f((unsigned short)v[2]), f3 = bf2f((unsigned short)v[3]);
    float f4 = bf2f((unsigned short)v[4]), f5 = bf2f((unsigned short)v[5]);
    float f6 = bf2f((unsigned short)v[6]), f7 = bf2f((unsigned short)v[7]);
    float s = (f0 + f1) + (f2 + f3) + (f4 + f5) + (f6 + f7);
    float q = f0*f0 + f1*f1 + f2*f2 + f3*f3 + f4*f4 + f5*f5 + f6*f6 + f7*f7;
#pragma unroll
    for (int m = 32; m >= 1; m >>= 1) { s += __shfl_xor(s, m); q += __shfl_xor(q, m); }
    float mean = s * (1.f / 512.f);
    float var  = q * (1.f / 512.f) - mean * mean;
    float rstd = 1.f / sqrtf(var + 1e-5f);
    *(short8v*)&As[row * 512 + ((lane * 8) ^ ((row & 7) << 3))] = v;
    if (lane == 0) { mS[row] = mean; rS[row] = rstd; meanA[grow] = mean; rstdA[grow] = rstd; }
  }
  // stage Wu k-phase 0 (cols [0,256)); Wu rows are 1024B, phase rows 512B
  const char* Wb = (const char*)WuP;
#pragma unroll
  for (int r = 0; r < 4; ++r) {
    int o = r * 8192 + tid * 16;
    int row = o >> 9, kb = o & 511;
    g2lds16(Wb + (size_t)row * 1024 + (size_t)(kb ^ ((row & 7) << 4)), (char*)Bs + o);
  }
  __syncthreads();   // drains ds_writes + global_load_lds

  // wave w: row-group rgrp = w>>2 (16 rows), col-tile ctile = w&3 (16 cols)
  const int rgrp = w >> 2, ctile = w & 3;
  f32x4 acc = {};
  const int rs = lane & 15, kx = (lane >> 4) * 8;
  const int key = (rs & 7) << 3;
  const int arow = (rgrp * 16 + rs) * 512;
  const int col = ctile * 16 + rs;
#pragma unroll
  for (int p = 0; p < 2; ++p) {
#pragma unroll
    for (int kt = 0; kt < 8; ++kt) {
      short8v a = *(const short8v*)&As[arow + ((p * 256 + kt * 32 + kx) ^ key)];
      short8v b = *(const short8v*)&Bs[col * 256 + ((kt * 32 + kx) ^ key)];
      acc = __builtin_amdgcn_mfma_f32_16x16x32_bf16(a, b, acc, 0, 0, 0);
    }
    if (p == 0) {      // swap in k-phase 1 (cols [256,512))
      __syncthreads();
#pragma unroll
      for (int r = 0; r < 4; ++r) {
        int o = r * 8192 + tid * 16;
        int row = o >> 9, kb = o & 511;
        g2lds16(Wb + (size_t)row * 1024 + 512 + (size_t)(kb ^ ((row & 7) << 4)),
                (char*)Bs + o);
      }
      __syncthreads();
    }
  }
  const int ccol = lane & 15, cr4 = (lane >> 4) * 4;
  {
    int ocol = ctile * 16 + ccol;
    float pc = Pu[ocol], c1 = Qu[ocol] + bu[ocol];
#pragma unroll
    for (int j = 0; j < 4; ++j) {
      int row = rgrp * 16 + cr4 + j;
      float sr = rS[row], mr = mS[row];
      float val = fmaf(sr, acc[j], fmaf(-mr * sr, pc, c1));
      u[(size_t)(row0 + row) * 64 + ocol] = f2bf(val);
    }
  }
}

// ---------------------------------------------------------------------------
// Fused gate + out-projection + residual (LN folded), XCD-grouped remap,
// 2-barrier BK=128 K-loop, 512 threads (8 waves 2x4, tile 64x32).
// ---------------------------------------------------------------------------
__global__ __launch_bounds__(512) void gemm_gateop(
    const unsigned short* __restrict__ x,     // [Mc,512] bf16 RAW
    const unsigned short* __restrict__ hs,    // [Mc,64]  bf16
    const unsigned short* __restrict__ WgP,   // [512,512] layer slice
    const unsigned short* __restrict__ WopB,  // [512,64]  layer slice
    const float* __restrict__ P, const float* __restrict__ Q,
    const float* __restrict__ bg, const float* __restrict__ bop,
    const float* __restrict__ meanA, const float* __restrict__ rstdA,
    unsigned short* __restrict__ xout) {      // [Mc,512] bf16
  __shared__ __align__(16) unsigned short As[128 * 128];   // 32KB, BK=128
  __shared__ __align__(16) unsigned short Bs[128 * 128];   // 32KB
  const int tid = threadIdx.x, lane = tid & 63, wave = tid >> 6;
  const int wr = wave >> 2, wc = wave & 3;   // 2 x 4 waves, tile 64x32
  // XCD-grouped bijective remap (grid = nrs*4, nrs multiple of 8):
  const int L = blockIdx.x;
  const int xcd = L & 7, rnd = L >> 3;
  const int row0 = ((rnd >> 2) * 8 + xcd) * 128;
  const int col0 = (rnd & 3) * 128;
  f32x4 accg[4][2] = {};
  f32x4 acco[4][2] = {};
  const int rs = lane & 15, kx = (lane >> 4) * 8;
  const int swu = (rs & 7) << 3;

  const char* Ab = (const char*)(x + (size_t)row0 * 512);
  const char* Bb = (const char*)(WgP + (size_t)col0 * 512);
  for (int kt = 0; kt < 4; ++kt) {
    stage_sw128<512>(Ab, (size_t)kt * 256, (char*)As, tid);
    stage_sw128<512>(Bb, (size_t)kt * 256, (char*)Bs, tid);
    __syncthreads();
#pragma unroll
    for (int kk = 0; kk < 4; ++kk) {
      const int ks = (kk * 32 + kx) ^ swu;
      short8v af[4], bfv[2];
#pragma unroll
      for (int m = 0; m < 4; ++m)
        af[m] = *(const short8v*)&As[(wr * 64 + m * 16 + rs) * 128 + ks];
#pragma unroll
      for (int n = 0; n < 2; ++n)
        bfv[n] = *(const short8v*)&Bs[(wc * 32 + n * 16 + rs) * 128 + ks];
#pragma unroll
      for (int m = 0; m < 4; ++m)
#pragma unroll
        for (int n = 0; n < 2; ++n)
          accg[m][n] = __builtin_amdgcn_mfma_f32_16x16x32_bf16(af[m], bfv[n], accg[m][n], 0, 0, 0);
    }
    __syncthreads();
  }

  // out-projection pass (K=64): hs/Wop tiles have 128B rows
  stage_sw<512, 128>((const char*)(hs + (size_t)row0 * 64), 128, 0, (char*)As, tid);
  stage_sw<512, 128>((const char*)(WopB + (size_t)col0 * 64), 128, 0, (char*)Bs, tid);
  __syncthreads();
#pragma unroll
  for (int kk = 0; kk < 2; ++kk) {
    const int ks = (kk * 32 + kx) ^ swu;
    short8v af[4], bfv[2];
#pragma unroll
    for (int m = 0; m < 4; ++m)
      af[m] = *(const short8v*)&As[(wr * 64 + m * 16 + rs) * 64 + ks];
#pragma unroll
    for (int n = 0; n < 2; ++n)
      bfv[n] = *(const short8v*)&Bs[(wc * 32 + n * 16 + rs) * 64 + ks];
#pragma unroll
    for (int m = 0; m < 4; ++m)
#pragma unroll
      for (int n = 0; n < 2; ++n)
        acco[m][n] = __builtin_amdgcn_mfma_f32_16x16x32_bf16(af[m], bfv[n], acco[m][n], 0, 0, 0);
  }

  // epilogue: C/D layout col=lane&15, row=(lane>>4)*4+reg
  const int ccol = lane & 15, cr4 = (lane >> 4) * 4;
#pragma unroll
  for (int m = 0; m < 4; ++m) {
    float sr4[4], mr4[4];
#pragma unroll
    for (int j = 0; j < 4; ++j) {
      int grow = row0 + wr * 64 + m * 16 + cr4 + j;
      sr4[j] = rstdA[grow];
      mr4[j] = meanA[grow];
    }
#pragma unroll
    for (int n = 0; n < 2; ++n) {
      int gcol = col0 + wc * 32 + n * 16 + ccol;
      float pc = P[gcol], c1 = Q[gcol] + bg[gcol], bov = bop[gcol];
#pragma unroll
      for (int j = 0; j < 4; ++j) {
        int grow = row0 + wr * 64 + m * 16 + cr4 + j;
        size_t idx = (size_t)grow * 512 + gcol;
        float gpre = fmaf(sr4[j], accg[m][n][j], fmaf(-mr4[j] * sr4[j], pc, c1));
        float gv = 1.f / (1.f + __expf(-gpre));
        float ov = acco[m][n][j] + bov;
        xout[idx] = f2bf(bf2f(x[idx]) + gv * ov);
      }
    }
  }
}

// ---------------------------------------------------------------------------
// Chunked tanh-RNN scan: one wave per (batch, 8-step chunk), 16-step warmup.
// 8192 waves (32 blocks/CU); contraction sigma_max(A)~0.16 -> warm-start
// error ~1e-11 (below bf16 resolution of hs).
// ---------------------------------------------------------------------------
__global__ __launch_bounds__(64) void scan_kernel(const unsigned short* __restrict__ u,
                                                  const float* __restrict__ A,
                                                  unsigned short* __restrict__ hs) {
  const int l = threadIdx.x;
  const int b = blockIdx.y, c = blockIdx.x;
  __shared__ float h[Sn];
  h[l] = 0.f;

  float4 Ar[16];
  const float4* Arow = (const float4*)(A + (size_t)l * Sn);
#pragma unroll
  for (int i = 0; i < 16; ++i) Ar[i] = Arow[i];

  int t0 = c * 8 - 16; if (t0 < 0) t0 = 0;
  const int tw = c * 8, tend = c * 8 + 8;
  const unsigned short* ub = u + (size_t)b * Tn * Sn;
  unsigned short* hb = hs + (size_t)b * Tn * Sn;

  unsigned short uraw = ub[(size_t)t0 * Sn + l];
  for (int t = t0; t < tend; ++t) {
    int tnext = t + 1 < Tn ? t + 1 : Tn - 1;
    unsigned short unext = ub[(size_t)tnext * Sn + l];
    const float4* h4 = (const float4*)h;
    float a0 = bf2f(uraw), a1 = 0.f, a2 = 0.f, a3 = 0.f;
#pragma unroll
    for (int i = 0; i < 16; i += 4) {
      float4 h0 = h4[i], h1 = h4[i + 1], h2 = h4[i + 2], h3 = h4[i + 3];
      a0 += Ar[i].x * h0.x + Ar[i].y * h0.y + Ar[i].z * h0.z + Ar[i].w * h0.w;
      a1 += Ar[i+1].x * h1.x + Ar[i+1].y * h1.y + Ar[i+1].z * h1.z + Ar[i+1].w * h1.w;
      a2 += Ar[i+2].x * h2.x + Ar[i+2].y * h2.y + Ar[i+2].z * h2.z + Ar[i+2].w * h2.w;
      a3 += Ar[i+3].x * h3.x + Ar[i+3].y * h3.y + Ar[i+3].z * h3.z + Ar[i+3].w * h3.w;
    }
    float sv = (a0 + a1) + (a2 + a3);
    sv = fminf(fmaxf(sv, -15.f), 15.f);
    float e = __expf(2.f * sv);
    float hn = __fdividef(e - 1.f, e + 1.f);   // tanh
    if (t >= tw) hb[(size_t)t * Sn + l] = f2bf(hn);
    h[l] = hn;          // single-wave lockstep
    uraw = unext;
  }
}

// ---------------------------------------------------------------------------
// Final LN + partial mean (deterministic two-stage), bf16 x input
// ---------------------------------------------------------------------------
__global__ __launch_bounds__(256) void final_ln_mean(const unsigned short* __restrict__ x,
                                                     const float* __restrict__ fw,
                                                     const float* __restrict__ fb,
                                                     float* __restrict__ part) {
  const int b = blockIdx.y, chunk = blockIdx.x;
  const int wave = threadIdx.x >> 6, lane = threadIdx.x & 63;
  const float4* wp = (const float4*)(fw + lane * 8);
  const float4* bp = (const float4*)(fb + lane * 8);
  float4 w0 = wp[0], w1 = wp[1], bb0 = bp[0], bb1 = bp[1];
  float acc[8] = {};
  for (int it = 0; it < 64; ++it) {
    int t = chunk * 256 + it * 4 + wave;
    short8v v = *(const short8v*)(x + ((size_t)b * Tn + t) * Dn + lane * 8);
    float f0 = bf2f((unsigned short)v[0]), f1 = bf2f((unsigned short)v[1]);
    float f2 = bf2f((unsigned short)v[2]), f3 = bf2f((unsigned short)v[3]);
    float f4 = bf2f((unsigned short)v[4]), f5 = bf2f((unsigned short)v[5]);
    float f6 = bf2f((unsigned short)v[6]), f7 = bf2f((unsigned short)v[7]);
    float s = (f0 + f1) + (f2 + f3) + (f4 + f5) + (f6 + f7);
#pragma unroll
    for (int m = 32; m >= 1; m >>= 1) s += __shfl_xor(s, m);
    float mean = s * (1.f / 512.f);
    float d0 = f0 - mean, d1 = f1 - mean, d2 = f2 - mean, d3 = f3 - mean;
    float d4 = f4 - mean, d5 = f5 - mean, d6 = f6 - mean, d7 = f7 - mean;
    float q = d0*d0 + d1*d1 + d2*d2 + d3*d3 + d4*d4 + d5*d5 + d6*d6 + d7*d7;
#pragma unroll
    for (int m = 32; m >= 1; m >>= 1) q += __shfl_xor(q, m);
    float rstd = 1.f / sqrtf(q * (1.f / 512.f) + 1e-5f);
    acc[0] += d0 * rstd * w0.x + bb0.x;
    acc[1] += d1 * rstd * w0.y + bb0.y;
    acc[2] += d2 * rstd * w0.z + bb0.z;
    acc[3] += d3 * rstd * w0.w + bb0.w;
    acc[4] += d4 * rstd * w1.x + bb1.x;
    acc[5] += d5 * rstd * w1.y + bb1.y;
    acc[6] += d6 * rstd * w1.z + bb1.z;
    acc[7] += d7 * rstd * w1.w + bb1.w;
  }
  __shared__ float red[4][512];
#pragma unroll
  for (int j = 0; j < 8; ++j) red[wave][lane * 8 + j] = acc[j];
  __syncthreads();
#pragma unroll
  for (int cc = 0; cc < 2; ++cc) {
    int cidx = threadIdx.x * 2 + cc;
    part[((size_t)(chunk * Bn + b)) * Dn + cidx] =
        red[0][cidx] + red[1][cidx] + red[2][cidx] + red[3][cidx];
  }
}

// ---------------------------------------------------------------------------
// Head (reduce_y merged): y = mean(part)/T; out = relu(y@W1^T+b1)@W2^T + b2
// ---------------------------------------------------------------------------
__global__ __launch_bounds__(256) void head_kernel(const float* __restrict__ part,
                                                   const float* __restrict__ W1,
                                                   const float* __restrict__ b1,
                                                   const float* __restrict__ W2,
                                                   const float* __restrict__ b2,
                                                   float* __restrict__ out) {
  const int b = blockIdx.x, j = threadIdx.x;
  __shared__ float ybuf[Dn];
  for (int d = j; d < Dn; d += 256) {
    float s = 0.f;
#pragma unroll
    for (int ch = 0; ch < 8; ++ch) s += part[((size_t)(ch * Bn + b)) * Dn + d];
    ybuf[d] = s * (1.f / 2048.f);
  }
  __syncthreads();
  const float4* wj = (const float4*)(W1 + (size_t)j * Dn);
  const float4* yb = (const float4*)ybuf;
  float a0 = 0.f, a1 = 0.f, a2 = 0.f, a3 = 0.f;
  for (int k = 0; k < 128; k += 4) {
    float4 q0 = wj[k], q1 = wj[k+1], q2 = wj[k+2], q3 = wj[k+3];
    float4 u0 = yb[k], u1 = yb[k+1], u2 = yb[k+2], u3 = yb[k+3];
    a0 += q0.x*u0.x + q0.y*u0.y + q0.z*u0.z + q0.w*u0.w;
    a1 += q1.x*u1.x + q1.y*u1.y + q1.z*u1.z + q1.w*u1.w;
    a2 += q2.x*u2.x + q2.y*u2.y + q2.z*u2.z + q2.w*u2.w;
    a3 += q3.x*u3.x + q3.y*u3.y + q3.z*u3.z + q3.w*u3.w;
  }
  float hv = fmaxf((a0 + a1) + (a2 + a3) + b1[j], 0.f);
  __shared__ float red[256];
  for (int c = 0; c < 2; ++c) {
    red[j] = hv * W2[c * 256 + j];
    __syncthreads();
    for (int s2 = 128; s2 > 0; s2 >>= 1) {
      if (j < s2) red[j] += red[j + s2];
      __syncthreads();
    }
    if (j == 0) out[b * 2 + c] = red[0] + b2[c];
    __syncthreads();
  }
}

// ---------------------------------------------------------------------------
// Workspace layout (bytes)
// ---------------------------------------------------------------------------
static constexpr size_t WGP_OFF  = 0;           // bf16 [L,D,D]   2097152
static constexpr size_t WUP_OFF  = 2097152;     // bf16 [L,S,D]    262144
static constexpr size_t WOPB_OFF = 2359296;     // bf16 [L,D,S]    262144
static constexpr size_t P_OFF    = 2621440;     // fp32 [L,D]        8192
static constexpr size_t Q_OFF    = 2629632;     // fp32 [L,D]        8192
static constexpr size_t PU_OFF   = 2637824;     // fp32 [L,S]        1024
static constexpr size_t QU_OFF   = 2638848;     // fp32 [L,S]        1024
static constexpr size_t BU_OFF   = 2639872;     // fp32 [L,S]        1024
static constexpr size_t PART_OFF = 2640896;     // fp32 [8,32,512] 524288
static constexpr size_t X_OFF    = 3165184;     // bf16 [B,T,D]  67108864
static constexpr size_t X2_OFF   = X_OFF + 67108864;
static constexpr size_t CH_OFF   = X2_OFF + 67108864;  // u/hs/mean/rstd

extern "C" void kernel_launch(void* const* d_in, const int* in_sizes, int n_in,
                              void* d_out, int out_size, void* d_ws, size_t ws_size,
                              hipStream_t stream) {
  const int*   tok  = (const int*)d_in[0];
  const float* emb  = (const float*)d_in[1];
  const float* ln_w = (const float*)d_in[2];
  const float* ln_b = (const float*)d_in[3];
  const float* Wsp  = (const float*)d_in[4];
  const float* bsp  = (const float*)d_in[5];
  const float* Wip  = (const float*)d_in[6];
  const float* bip  = (const float*)d_in[7];
  const float* Wop  = (const float*)d_in[8];
  const float* bop  = (const float*)d_in[9];
  const float* Wg   = (const float*)d_in[10];
  const float* bg   = (const float*)d_in[11];
  const float* Am   = (const float*)d_in[12];
  const float* fw   = (const float*)d_in[13];
  const float* fb   = (const float*)d_in[14];
  const float* W1   = (const float*)d_in[15];
  const float* b1   = (const float*)d_in[16];
  const float* W2   = (const float*)d_in[17];
  const float* b2   = (const float*)d_in[18];

  char* ws = (char*)d_ws;
  unsigned short* WgP  = (unsigned short*)(ws + WGP_OFF);
  unsigned short* WuP  = (unsigned short*)(ws + WUP_OFF);
  unsigned short* WopB = (unsigned short*)(ws + WOPB_OFF);
  float* Pg  = (float*)(ws + P_OFF);
  float* Qg  = (float*)(ws + Q_OFF);
  float* Pu  = (float*)(ws + PU_OFF);
  float* Qu  = (float*)(ws + QU_OFF);
  float* bu  = (float*)(ws + BU_OFF);
  float* part= (float*)(ws + PART_OFF);
  unsigned short* xA = (unsigned short*)(ws + X_OFF);
  unsigned short* xB = (unsigned short*)(ws + X2_OFF);
  float* outp = (float*)d_out;

  // chunking (u 128B/row + hs 128B/row + mean 4 + rstd 4 = 264 B/row)
  int nch = 32;
  for (int c = 1; c <= 32; c <<= 1) {
    size_t Mc = (size_t)Mrows / c;
    if (CH_OFF + 264ull * Mc <= ws_size) { nch = c; break; }
  }
  const int nb = Bn / nch;
  const size_t Mc = (size_t)Mrows / nch;
  unsigned short* u    = (unsigned short*)(ws + CH_OFF);
  unsigned short* hs   = (unsigned short*)(ws + CH_OFF + 128ull * Mc);
  float*          mean = (float*)(ws + CH_OFF + 256ull * Mc);
  float*          rstd = (float*)(ws + CH_OFF + 260ull * Mc);

  prep_kernel<<<1088, 256, 0, stream>>>(Wg, Wop, Wsp, Wip, bsp, bip, ln_w, ln_b,
                                        WgP, WuP, WopB, Pg, Qg, Pu, Qu, bu);

  for (int l = 0; l < Lk; ++l) {
    unsigned short* src = (l & 1) ? xB : xA;
    unsigned short* dst = (l & 1) ? xA : xB;
    for (int c = 0; c < nch; ++c) {
      unsigned short* xs = src + (size_t)c * Mc * Dn;
      unsigned short* xd = dst + (size_t)c * Mc * Dn;
      if (l == 0)
        ln_u_kernel<1><<<(int)(Mc / 32), 512, 0, stream>>>(
            nullptr, tok + (size_t)c * Mc, emb, xs,
            WuP + (size_t)l * Sn * Dn, Pu + l * Sn, Qu + l * Sn, bu + l * Sn,
            u, mean, rstd);
      else
        ln_u_kernel<0><<<(int)(Mc / 32), 512, 0, stream>>>(
            xs, nullptr, nullptr, nullptr,
            WuP + (size_t)l * Sn * Dn, Pu + l * Sn, Qu + l * Sn, bu + l * Sn,
            u, mean, rstd);
      scan_kernel<<<dim3(Tn / 8, nb), 64, 0, stream>>>(
          u, Am + (size_t)l * Sn * Sn, hs);
      gemm_gateop<<<(int)(Mc / 128) * 4, 512, 0, stream>>>(
          xs, hs, WgP + (size_t)l * Dn * Dn, WopB + (size_t)l * Dn * Sn,
          Pg + l * Dn, Qg + l * Dn, bg + l * Dn, bop + l * Dn,
          mean, rstd, xd);
    }
  }

  // after L=4 layers (even), final residual is back in xA
  final_ln_mean<<<dim3(8, Bn), 256, 0, stream>>>(xA, fw, fb, part);
  head_kernel<<<Bn, 256, 0, stream>>>(part, W1, b1, W2, b2, outp);
}

// Round 22
// 597.703 us; speedup vs baseline: 1.0776x; 1.0776x over previous
//
#include <hip/hip_runtime.h>

// ---------------------------------------------------------------------------
// SimplifiedMambaModel on MI355X (gfx950)   -- r20 configuration (best: 600us)
// B=32 T=2048 D=512 S=64 L=4 V=32000 C=2
//  - LN folded into weights (gate = s_r*(x@Wg'^T) - m_r*s_r*P + Q); GEMMs
//    consume RAW bf16 x; no xn tensor
//  - residual ping-pong x <-> x2 (bf16)
//  - gateop: 2-barrier BK=128 + XCD remap, 512 threads (68us proven)
//  - ln_u: 512 threads, 32 rows/block
//  - scan: 16-step chunks (optimum of warmup/concurrency tradeoff)
// ---------------------------------------------------------------------------

#define DEV __device__ __forceinline__

typedef __attribute__((ext_vector_type(8))) short short8v;   // 8 x bf16
typedef __attribute__((ext_vector_type(4))) float f32x4;     // MFMA C/D frag

static constexpr int Bn = 32, Tn = 2048, Dn = 512, Sn = 64, Lk = 4;
static constexpr int Mrows = Bn * Tn;  // 65536

DEV unsigned short f2bf(float f) {          // RNE float->bf16
  unsigned u = __float_as_uint(f);
  u += 0x7fffu + ((u >> 16) & 1u);
  return (unsigned short)(u >> 16);
}
DEV float bf2f(unsigned short h) { return __uint_as_float(((unsigned)h) << 16); }

DEV void g2lds16(const void* g, void* l) {
  __builtin_amdgcn_global_load_lds(
      (const __attribute__((address_space(1))) void*)g,
      (__attribute__((address_space(3))) void*)l, 16, 0, 0);
}

// Stage a [ROWS x 64-bf16] tile (128B LDS rows) with T2 XOR swizzle.
// Readers XOR full ushort col index with ((row&7)<<3).
template <int THREADS, int ROWS>
DEV void stage_sw(const char* gbase, size_t rowStride, size_t kOff, char* lds, int tid) {
#pragma unroll
  for (int r = 0; r < ROWS * 128 / (THREADS * 16); ++r) {
    int o = r * THREADS * 16 + tid * 16;
    int row = o >> 7, kb = o & 127;
    g2lds16(gbase + (size_t)row * rowStride + kOff + (size_t)(kb ^ ((row & 7) << 4)),
            lds + o);
  }
}

// Stage a [128 x 128-bf16] tile (256B LDS rows) with the same per-128B-window
// XOR swizzle; global rows are 1024B (x / WgP).
template <int THREADS>
DEV void stage_sw128(const char* gbase, size_t kOff, char* lds, int tid) {
#pragma unroll
  for (int r = 0; r < 32768 / (THREADS * 16); ++r) {
    int o = r * THREADS * 16 + tid * 16;
    int row = o >> 8, kb = o & 255;
    g2lds16(gbase + (size_t)row * 1024 + kOff + (size_t)(kb ^ ((row & 7) << 4)),
            lds + o);
  }
}

// ---------------------------------------------------------------------------
// Weight prep: folded weights + column sums.
// ---------------------------------------------------------------------------
__global__ __launch_bounds__(256) void prep_kernel(
    const float* __restrict__ Wg, const float* __restrict__ Wop,
    const float* __restrict__ Wsp, const float* __restrict__ Wip,
    const float* __restrict__ bsp, const float* __restrict__ bip,
    const float* __restrict__ lnw, const float* __restrict__ lnb,
    unsigned short* __restrict__ WgP, unsigned short* __restrict__ WuP,
    unsigned short* __restrict__ WopB,
    float* __restrict__ P, float* __restrict__ Q,
    float* __restrict__ Pu, float* __restrict__ Qu, float* __restrict__ bu) {
  const int blk = blockIdx.x, tid = threadIdx.x, lane = tid & 63, w = tid >> 6;
  if (blk < 512) {
    int idx = blk * 4 + w;                  // = l*512 + col
    int l = idx >> 9;
    const float* src = Wg + (size_t)idx * 512;
    const float* gw = lnw + (size_t)l * 512;
    const float* gb = lnb + (size_t)l * 512;
    unsigned short* dst = WgP + (size_t)idx * 512;
    float p = 0.f, q = 0.f;
#pragma unroll
    for (int e = 0; e < 8; ++e) {
      int k = lane * 8 + e;
      float wv = src[k];
      unsigned short hb = f2bf(gw[k] * wv);
      dst[k] = hb;
      p += bf2f(hb);
      q += gb[k] * wv;
    }
#pragma unroll
    for (int m = 32; m >= 1; m >>= 1) { p += __shfl_xor(p, m); q += __shfl_xor(q, m); }
    if (lane == 0) { P[idx] = p; Q[idx] = q; }
  } else if (blk < 576) {
    int idx = (blk - 512) * 4 + w;          // = l*64 + col
    int l = idx >> 6;
    const float* s1 = Wsp + (size_t)idx * 512;
    const float* s2 = Wip + (size_t)idx * 512;
    const float* gw = lnw + (size_t)l * 512;
    const float* gb = lnb + (size_t)l * 512;
    unsigned short* dst = WuP + (size_t)idx * 512;
    float p = 0.f, q = 0.f;
#pragma unroll
    for (int e = 0; e < 8; ++e) {
      int k = lane * 8 + e;
      float wv = s1[k] + s2[k];
      unsigned short hb = f2bf(gw[k] * wv);
      dst[k] = hb;
      p += bf2f(hb);
      q += gb[k] * wv;
    }
#pragma unroll
    for (int m = 32; m >= 1; m >>= 1) { p += __shfl_xor(p, m); q += __shfl_xor(q, m); }
    if (lane == 0) { Pu[idx] = p; Qu[idx] = q; bu[idx] = bsp[idx] + bip[idx]; }
  } else {
    int i = (blk - 576) * 256 + tid;
    if (i < Lk * Dn * Sn) WopB[i] = f2bf(Wop[i]);
  }
}

// ---------------------------------------------------------------------------
// Fused (embed +) LN-stats + u-projection.  32 rows/block, 512 threads
// (8 waves: 2 row-groups x 4 col-tiles).  As 32KB + Bs 32KB = 64KB ->
// 2 blocks/CU = 16 waves/CU.   u = s*(x@WuP^T) - m*s*Pu + Qu + bu
// ---------------------------------------------------------------------------
template <int EMB>
__global__ __launch_bounds__(512) void ln_u_kernel(
    const unsigned short* __restrict__ x,    // [Mc,512] bf16 (EMB=0)
    const int* __restrict__ tok,             // EMB=1
    const float* __restrict__ emb,           // EMB=1
    unsigned short* __restrict__ xw,         // EMB=1: write x
    const unsigned short* __restrict__ WuP,  // [64,512] layer slice
    const float* __restrict__ Pu, const float* __restrict__ Qu,
    const float* __restrict__ bu,
    unsigned short* __restrict__ u,          // [Mc,64] bf16
    float* __restrict__ meanA, float* __restrict__ rstdA) {
  __shared__ __align__(16) unsigned short As[32 * 512];   // raw x, swizzled
  __shared__ __align__(16) unsigned short Bs[64 * 256];   // Wu k-phase, swz
  __shared__ float mS[32], rS[32];
  const int tid = threadIdx.x, lane = tid & 63, w = tid >> 6;
  const int row0 = blockIdx.x * 32;

#pragma unroll
  for (int i = 0; i < 4; ++i) {
    int row = w * 4 + i;
    size_t grow = (size_t)(row0 + row);
    short8v v;
    if (EMB) {
      int t = tok[grow];
      const float4* src = (const float4*)(emb + (size_t)t * Dn + lane * 8);
      float4 a = src[0], b = src[1];
      const float scale = 22.627416997969522f;   // sqrt(512)
      v[0] = (short)f2bf(a.x * scale); v[1] = (short)f2bf(a.y * scale);
      v[2] = (short)f2bf(a.z * scale); v[3] = (short)f2bf(a.w * scale);
      v[4] = (short)f2bf(b.x * scale); v[5] = (short)f2bf(b.y * scale);
      v[6] = (short)f2bf(b.z * scale); v[7] = (short)f2bf(b.w * scale);
      *(short8v*)(xw + grow * 512 + lane * 8) = v;
    } else {
      v = *(const short8v*)(x + grow * 512 + lane * 8);
    }
    float f0 = bf2f((unsigned short)v[0]), f1 = bf2f((unsigned short)v[1]);
    float f2 = bf2f((unsigned short)v[2]), f3 = bf2f((unsigned short)v[3]);
    float f4 = bf2f((unsigned short)v[4]), f5 = bf2f((unsigned short)v[5]);
    float f6 = bf2f((unsigned short)v[6]), f7 = bf2f((unsigned short)v[7]);
    float s = (f0 + f1) + (f2 + f3) + (f4 + f5) + (f6 + f7);
    float q = f0*f0 + f1*f1 + f2*f2 + f3*f3 + f4*f4 + f5*f5 + f6*f6 + f7*f7;
#pragma unroll
    for (int m = 32; m >= 1; m >>= 1) { s += __shfl_xor(s, m); q += __shfl_xor(q, m); }
    float mean = s * (1.f / 512.f);
    float var  = q * (1.f / 512.f) - mean * mean;
    float rstd = 1.f / sqrtf(var + 1e-5f);
    *(short8v*)&As[row * 512 + ((lane * 8) ^ ((row & 7) << 3))] = v;
    if (lane == 0) { mS[row] = mean; rS[row] = rstd; meanA[grow] = mean; rstdA[grow] = rstd; }
  }
  // stage Wu k-phase 0 (cols [0,256)); Wu rows are 1024B, phase rows 512B
  const char* Wb = (const char*)WuP;
#pragma unroll
  for (int r = 0; r < 4; ++r) {
    int o = r * 8192 + tid * 16;
    int row = o >> 9, kb = o & 511;
    g2lds16(Wb + (size_t)row * 1024 + (size_t)(kb ^ ((row & 7) << 4)), (char*)Bs + o);
  }
  __syncthreads();   // drains ds_writes + global_load_lds

  // wave w: row-group rgrp = w>>2 (16 rows), col-tile ctile = w&3 (16 cols)
  const int rgrp = w >> 2, ctile = w & 3;
  f32x4 acc = {};
  const int rs = lane & 15, kx = (lane >> 4) * 8;
  const int key = (rs & 7) << 3;
  const int arow = (rgrp * 16 + rs) * 512;
  const int col = ctile * 16 + rs;
#pragma unroll
  for (int p = 0; p < 2; ++p) {
#pragma unroll
    for (int kt = 0; kt < 8; ++kt) {
      short8v a = *(const short8v*)&As[arow + ((p * 256 + kt * 32 + kx) ^ key)];
      short8v b = *(const short8v*)&Bs[col * 256 + ((kt * 32 + kx) ^ key)];
      acc = __builtin_amdgcn_mfma_f32_16x16x32_bf16(a, b, acc, 0, 0, 0);
    }
    if (p == 0) {      // swap in k-phase 1 (cols [256,512))
      __syncthreads();
#pragma unroll
      for (int r = 0; r < 4; ++r) {
        int o = r * 8192 + tid * 16;
        int row = o >> 9, kb = o & 511;
        g2lds16(Wb + (size_t)row * 1024 + 512 + (size_t)(kb ^ ((row & 7) << 4)),
                (char*)Bs + o);
      }
      __syncthreads();
    }
  }
  const int ccol = lane & 15, cr4 = (lane >> 4) * 4;
  {
    int ocol = ctile * 16 + ccol;
    float pc = Pu[ocol], c1 = Qu[ocol] + bu[ocol];
#pragma unroll
    for (int j = 0; j < 4; ++j) {
      int row = rgrp * 16 + cr4 + j;
      float sr = rS[row], mr = mS[row];
      float val = fmaf(sr, acc[j], fmaf(-mr * sr, pc, c1));
      u[(size_t)(row0 + row) * 64 + ocol] = f2bf(val);
    }
  }
}

// ---------------------------------------------------------------------------
// Fused gate + out-projection + residual (LN folded), XCD-grouped remap,
// 2-barrier BK=128 K-loop, 512 threads (8 waves 2x4, tile 64x32).
// ---------------------------------------------------------------------------
__global__ __launch_bounds__(512) void gemm_gateop(
    const unsigned short* __restrict__ x,     // [Mc,512] bf16 RAW
    const unsigned short* __restrict__ hs,    // [Mc,64]  bf16
    const unsigned short* __restrict__ WgP,   // [512,512] layer slice
    const unsigned short* __restrict__ WopB,  // [512,64]  layer slice
    const float* __restrict__ P, const float* __restrict__ Q,
    const float* __restrict__ bg, const float* __restrict__ bop,
    const float* __restrict__ meanA, const float* __restrict__ rstdA,
    unsigned short* __restrict__ xout) {      // [Mc,512] bf16
  __shared__ __align__(16) unsigned short As[128 * 128];   // 32KB, BK=128
  __shared__ __align__(16) unsigned short Bs[128 * 128];   // 32KB
  const int tid = threadIdx.x, lane = tid & 63, wave = tid >> 6;
  const int wr = wave >> 2, wc = wave & 3;   // 2 x 4 waves, tile 64x32
  // XCD-grouped bijective remap (grid = nrs*4, nrs multiple of 8):
  const int L = blockIdx.x;
  const int xcd = L & 7, rnd = L >> 3;
  const int row0 = ((rnd >> 2) * 8 + xcd) * 128;
  const int col0 = (rnd & 3) * 128;
  f32x4 accg[4][2] = {};
  f32x4 acco[4][2] = {};
  const int rs = lane & 15, kx = (lane >> 4) * 8;
  const int swu = (rs & 7) << 3;

  const char* Ab = (const char*)(x + (size_t)row0 * 512);
  const char* Bb = (const char*)(WgP + (size_t)col0 * 512);
  for (int kt = 0; kt < 4; ++kt) {
    stage_sw128<512>(Ab, (size_t)kt * 256, (char*)As, tid);
    stage_sw128<512>(Bb, (size_t)kt * 256, (char*)Bs, tid);
    __syncthreads();
#pragma unroll
    for (int kk = 0; kk < 4; ++kk) {
      const int ks = (kk * 32 + kx) ^ swu;
      short8v af[4], bfv[2];
#pragma unroll
      for (int m = 0; m < 4; ++m)
        af[m] = *(const short8v*)&As[(wr * 64 + m * 16 + rs) * 128 + ks];
#pragma unroll
      for (int n = 0; n < 2; ++n)
        bfv[n] = *(const short8v*)&Bs[(wc * 32 + n * 16 + rs) * 128 + ks];
#pragma unroll
      for (int m = 0; m < 4; ++m)
#pragma unroll
        for (int n = 0; n < 2; ++n)
          accg[m][n] = __builtin_amdgcn_mfma_f32_16x16x32_bf16(af[m], bfv[n], accg[m][n], 0, 0, 0);
    }
    __syncthreads();
  }

  // out-projection pass (K=64): hs/Wop tiles have 128B rows
  stage_sw<512, 128>((const char*)(hs + (size_t)row0 * 64), 128, 0, (char*)As, tid);
  stage_sw<512, 128>((const char*)(WopB + (size_t)col0 * 64), 128, 0, (char*)Bs, tid);
  __syncthreads();
#pragma unroll
  for (int kk = 0; kk < 2; ++kk) {
    const int ks = (kk * 32 + kx) ^ swu;
    short8v af[4], bfv[2];
#pragma unroll
    for (int m = 0; m < 4; ++m)
      af[m] = *(const short8v*)&As[(wr * 64 + m * 16 + rs) * 64 + ks];
#pragma unroll
    for (int n = 0; n < 2; ++n)
      bfv[n] = *(const short8v*)&Bs[(wc * 32 + n * 16 + rs) * 64 + ks];
#pragma unroll
    for (int m = 0; m < 4; ++m)
#pragma unroll
      for (int n = 0; n < 2; ++n)
        acco[m][n] = __builtin_amdgcn_mfma_f32_16x16x32_bf16(af[m], bfv[n], acco[m][n], 0, 0, 0);
  }

  // epilogue: C/D layout col=lane&15, row=(lane>>4)*4+reg
  const int ccol = lane & 15, cr4 = (lane >> 4) * 4;
#pragma unroll
  for (int m = 0; m < 4; ++m) {
    float sr4[4], mr4[4];
#pragma unroll
    for (int j = 0; j < 4; ++j) {
      int grow = row0 + wr * 64 + m * 16 + cr4 + j;
      sr4[j] = rstdA[grow];
      mr4[j] = meanA[grow];
    }
#pragma unroll
    for (int n = 0; n < 2; ++n) {
      int gcol = col0 + wc * 32 + n * 16 + ccol;
      float pc = P[gcol], c1 = Q[gcol] + bg[gcol], bov = bop[gcol];
#pragma unroll
      for (int j = 0; j < 4; ++j) {
        int grow = row0 + wr * 64 + m * 16 + cr4 + j;
        size_t idx = (size_t)grow * 512 + gcol;
        float gpre = fmaf(sr4[j], accg[m][n][j], fmaf(-mr4[j] * sr4[j], pc, c1));
        float gv = 1.f / (1.f + __expf(-gpre));
        float ov = acco[m][n][j] + bov;
        xout[idx] = f2bf(bf2f(x[idx]) + gv * ov);
      }
    }
  }
}

// ---------------------------------------------------------------------------
// Chunked tanh-RNN scan: one wave per (batch, 16-step chunk), 16-step warmup.
// 4096 waves (4/SIMD); contraction sigma_max(A)~0.16 -> warm-start error
// ~1e-11 (below bf16 resolution of hs).
// ---------------------------------------------------------------------------
__global__ __launch_bounds__(64) void scan_kernel(const unsigned short* __restrict__ u,
                                                  const float* __restrict__ A,
                                                  unsigned short* __restrict__ hs) {
  const int l = threadIdx.x;
  const int b = blockIdx.y, c = blockIdx.x;
  __shared__ float h[Sn];
  h[l] = 0.f;

  float4 Ar[16];
  const float4* Arow = (const float4*)(A + (size_t)l * Sn);
#pragma unroll
  for (int i = 0; i < 16; ++i) Ar[i] = Arow[i];

  int t0 = c * 16 - 16; if (t0 < 0) t0 = 0;
  const int tw = c * 16, tend = c * 16 + 16;
  const unsigned short* ub = u + (size_t)b * Tn * Sn;
  unsigned short* hb = hs + (size_t)b * Tn * Sn;

  unsigned short uraw = ub[(size_t)t0 * Sn + l];
  for (int t = t0; t < tend; ++t) {
    int tnext = t + 1 < Tn ? t + 1 : Tn - 1;
    unsigned short unext = ub[(size_t)tnext * Sn + l];
    const float4* h4 = (const float4*)h;
    float a0 = bf2f(uraw), a1 = 0.f, a2 = 0.f, a3 = 0.f;
#pragma unroll
    for (int i = 0; i < 16; i += 4) {
      float4 h0 = h4[i], h1 = h4[i + 1], h2 = h4[i + 2], h3 = h4[i + 3];
      a0 += Ar[i].x * h0.x + Ar[i].y * h0.y + Ar[i].z * h0.z + Ar[i].w * h0.w;
      a1 += Ar[i+1].x * h1.x + Ar[i+1].y * h1.y + Ar[i+1].z * h1.z + Ar[i+1].w * h1.w;
      a2 += Ar[i+2].x * h2.x + Ar[i+2].y * h2.y + Ar[i+2].z * h2.z + Ar[i+2].w * h2.w;
      a3 += Ar[i+3].x * h3.x + Ar[i+3].y * h3.y + Ar[i+3].z * h3.z + Ar[i+3].w * h3.w;
    }
    float sv = (a0 + a1) + (a2 + a3);
    sv = fminf(fmaxf(sv, -15.f), 15.f);
    float e = __expf(2.f * sv);
    float hn = __fdividef(e - 1.f, e + 1.f);   // tanh
    if (t >= tw) hb[(size_t)t * Sn + l] = f2bf(hn);
    h[l] = hn;          // single-wave lockstep
    uraw = unext;
  }
}

// ---------------------------------------------------------------------------
// Final LN + partial mean (deterministic two-stage), bf16 x input
// ---------------------------------------------------------------------------
__global__ __launch_bounds__(256) void final_ln_mean(const unsigned short* __restrict__ x,
                                                     const float* __restrict__ fw,
                                                     const float* __restrict__ fb,
                                                     float* __restrict__ part) {
  const int b = blockIdx.y, chunk = blockIdx.x;
  const int wave = threadIdx.x >> 6, lane = threadIdx.x & 63;
  const float4* wp = (const float4*)(fw + lane * 8);
  const float4* bp = (const float4*)(fb + lane * 8);
  float4 w0 = wp[0], w1 = wp[1], bb0 = bp[0], bb1 = bp[1];
  float acc[8] = {};
  for (int it = 0; it < 64; ++it) {
    int t = chunk * 256 + it * 4 + wave;
    short8v v = *(const short8v*)(x + ((size_t)b * Tn + t) * Dn + lane * 8);
    float f0 = bf2f((unsigned short)v[0]), f1 = bf2f((unsigned short)v[1]);
    float f2 = bf2f((unsigned short)v[2]), f3 = bf2f((unsigned short)v[3]);
    float f4 = bf2f((unsigned short)v[4]), f5 = bf2f((unsigned short)v[5]);
    float f6 = bf2f((unsigned short)v[6]), f7 = bf2f((unsigned short)v[7]);
    float s = (f0 + f1) + (f2 + f3) + (f4 + f5) + (f6 + f7);
#pragma unroll
    for (int m = 32; m >= 1; m >>= 1) s += __shfl_xor(s, m);
    float mean = s * (1.f / 512.f);
    float d0 = f0 - mean, d1 = f1 - mean, d2 = f2 - mean, d3 = f3 - mean;
    float d4 = f4 - mean, d5 = f5 - mean, d6 = f6 - mean, d7 = f7 - mean;
    float q = d0*d0 + d1*d1 + d2*d2 + d3*d3 + d4*d4 + d5*d5 + d6*d6 + d7*d7;
#pragma unroll
    for (int m = 32; m >= 1; m >>= 1) q += __shfl_xor(q, m);
    float rstd = 1.f / sqrtf(q * (1.f / 512.f) + 1e-5f);
    acc[0] += d0 * rstd * w0.x + bb0.x;
    acc[1] += d1 * rstd * w0.y + bb0.y;
    acc[2] += d2 * rstd * w0.z + bb0.z;
    acc[3] += d3 * rstd * w0.w + bb0.w;
    acc[4] += d4 * rstd * w1.x + bb1.x;
    acc[5] += d5 * rstd * w1.y + bb1.y;
    acc[6] += d6 * rstd * w1.z + bb1.z;
    acc[7] += d7 * rstd * w1.w + bb1.w;
  }
  __shared__ float red[4][512];
#pragma unroll
  for (int j = 0; j < 8; ++j) red[wave][lane * 8 + j] = acc[j];
  __syncthreads();
#pragma unroll
  for (int cc = 0; cc < 2; ++cc) {
    int cidx = threadIdx.x * 2 + cc;
    part[((size_t)(chunk * Bn + b)) * Dn + cidx] =
        red[0][cidx] + red[1][cidx] + red[2][cidx] + red[3][cidx];
  }
}

// ---------------------------------------------------------------------------
// Head (reduce_y merged): y = mean(part)/T; out = relu(y@W1^T+b1)@W2^T + b2
// ---------------------------------------------------------------------------
__global__ __launch_bounds__(256) void head_kernel(const float* __restrict__ part,
                                                   const float* __restrict__ W1,
                                                   const float* __restrict__ b1,
                                                   const float* __restrict__ W2,
                                                   const float* __restrict__ b2,
                                                   float* __restrict__ out) {
  const int b = blockIdx.x, j = threadIdx.x;
  __shared__ float ybuf[Dn];
  for (int d = j; d < Dn; d += 256) {
    float s = 0.f;
#pragma unroll
    for (int ch = 0; ch < 8; ++ch) s += part[((size_t)(ch * Bn + b)) * Dn + d];
    ybuf[d] = s * (1.f / 2048.f);
  }
  __syncthreads();
  const float4* wj = (const float4*)(W1 + (size_t)j * Dn);
  const float4* yb = (const float4*)ybuf;
  float a0 = 0.f, a1 = 0.f, a2 = 0.f, a3 = 0.f;
  for (int k = 0; k < 128; k += 4) {
    float4 q0 = wj[k], q1 = wj[k+1], q2 = wj[k+2], q3 = wj[k+3];
    float4 u0 = yb[k], u1 = yb[k+1], u2 = yb[k+2], u3 = yb[k+3];
    a0 += q0.x*u0.x + q0.y*u0.y + q0.z*u0.z + q0.w*u0.w;
    a1 += q1.x*u1.x + q1.y*u1.y + q1.z*u1.z + q1.w*u1.w;
    a2 += q2.x*u2.x + q2.y*u2.y + q2.z*u2.z + q2.w*u2.w;
    a3 += q3.x*u3.x + q3.y*u3.y + q3.z*u3.z + q3.w*u3.w;
  }
  float hv = fmaxf((a0 + a1) + (a2 + a3) + b1[j], 0.f);
  __shared__ float red[256];
  for (int c = 0; c < 2; ++c) {
    red[j] = hv * W2[c * 256 + j];
    __syncthreads();
    for (int s2 = 128; s2 > 0; s2 >>= 1) {
      if (j < s2) red[j] += red[j + s2];
      __syncthreads();
    }
    if (j == 0) out[b * 2 + c] = red[0] + b2[c];
    __syncthreads();
  }
}

// ---------------------------------------------------------------------------
// Workspace layout (bytes)
// ---------------------------------------------------------------------------
static constexpr size_t WGP_OFF  = 0;           // bf16 [L,D,D]   2097152
static constexpr size_t WUP_OFF  = 2097152;     // bf16 [L,S,D]    262144
static constexpr size_t WOPB_OFF = 2359296;     // bf16 [L,D,S]    262144
static constexpr size_t P_OFF    = 2621440;     // fp32 [L,D]        8192
static constexpr size_t Q_OFF    = 2629632;     // fp32 [L,D]        8192
static constexpr size_t PU_OFF   = 2637824;     // fp32 [L,S]        1024
static constexpr size_t QU_OFF   = 2638848;     // fp32 [L,S]        1024
static constexpr size_t BU_OFF   = 2639872;     // fp32 [L,S]        1024
static constexpr size_t PART_OFF = 2640896;     // fp32 [8,32,512] 524288
static constexpr size_t X_OFF    = 3165184;     // bf16 [B,T,D]  67108864
static constexpr size_t X2_OFF   = X_OFF + 67108864;
static constexpr size_t CH_OFF   = X2_OFF + 67108864;  // u/hs/mean/rstd

extern "C" void kernel_launch(void* const* d_in, const int* in_sizes, int n_in,
                              void* d_out, int out_size, void* d_ws, size_t ws_size,
                              hipStream_t stream) {
  const int*   tok  = (const int*)d_in[0];
  const float* emb  = (const float*)d_in[1];
  const float* ln_w = (const float*)d_in[2];
  const float* ln_b = (const float*)d_in[3];
  const float* Wsp  = (const float*)d_in[4];
  const float* bsp  = (const float*)d_in[5];
  const float* Wip  = (const float*)d_in[6];
  const float* bip  = (const float*)d_in[7];
  const float* Wop  = (const float*)d_in[8];
  const float* bop  = (const float*)d_in[9];
  const float* Wg   = (const float*)d_in[10];
  const float* bg   = (const float*)d_in[11];
  const float* Am   = (const float*)d_in[12];
  const float* fw   = (const float*)d_in[13];
  const float* fb   = (const float*)d_in[14];
  const float* W1   = (const float*)d_in[15];
  const float* b1   = (const float*)d_in[16];
  const float* W2   = (const float*)d_in[17];
  const float* b2   = (const float*)d_in[18];

  char* ws = (char*)d_ws;
  unsigned short* WgP  = (unsigned short*)(ws + WGP_OFF);
  unsigned short* WuP  = (unsigned short*)(ws + WUP_OFF);
  unsigned short* WopB = (unsigned short*)(ws + WOPB_OFF);
  float* Pg  = (float*)(ws + P_OFF);
  float* Qg  = (float*)(ws + Q_OFF);
  float* Pu  = (float*)(ws + PU_OFF);
  float* Qu  = (float*)(ws + QU_OFF);
  float* bu  = (float*)(ws + BU_OFF);
  float* part= (float*)(ws + PART_OFF);
  unsigned short* xA = (unsigned short*)(ws + X_OFF);
  unsigned short* xB = (unsigned short*)(ws + X2_OFF);
  float* outp = (float*)d_out;

  // chunking (u 128B/row + hs 128B/row + mean 4 + rstd 4 = 264 B/row)
  int nch = 32;
  for (int c = 1; c <= 32; c <<= 1) {
    size_t Mc = (size_t)Mrows / c;
    if (CH_OFF + 264ull * Mc <= ws_size) { nch = c; break; }
  }
  const int nb = Bn / nch;
  const size_t Mc = (size_t)Mrows / nch;
  unsigned short* u    = (unsigned short*)(ws + CH_OFF);
  unsigned short* hs   = (unsigned short*)(ws + CH_OFF + 128ull * Mc);
  float*          mean = (float*)(ws + CH_OFF + 256ull * Mc);
  float*          rstd = (float*)(ws + CH_OFF + 260ull * Mc);

  prep_kernel<<<1088, 256, 0, stream>>>(Wg, Wop, Wsp, Wip, bsp, bip, ln_w, ln_b,
                                        WgP, WuP, WopB, Pg, Qg, Pu, Qu, bu);

  for (int l = 0; l < Lk; ++l) {
    unsigned short* src = (l & 1) ? xB : xA;
    unsigned short* dst = (l & 1) ? xA : xB;
    for (int c = 0; c < nch; ++c) {
      unsigned short* xs = src + (size_t)c * Mc * Dn;
      unsigned short* xd = dst + (size_t)c * Mc * Dn;
      if (l == 0)
        ln_u_kernel<1><<<(int)(Mc / 32), 512, 0, stream>>>(
            nullptr, tok + (size_t)c * Mc, emb, xs,
            WuP + (size_t)l * Sn * Dn, Pu + l * Sn, Qu + l * Sn, bu + l * Sn,
            u, mean, rstd);
      else
        ln_u_kernel<0><<<(int)(Mc / 32), 512, 0, stream>>>(
            xs, nullptr, nullptr, nullptr,
            WuP + (size_t)l * Sn * Dn, Pu + l * Sn, Qu + l * Sn, bu + l * Sn,
            u, mean, rstd);
      scan_kernel<<<dim3(Tn / 16, nb), 64, 0, stream>>>(
          u, Am + (size_t)l * Sn * Sn, hs);
      gemm_gateop<<<(int)(Mc / 128) * 4, 512, 0, stream>>>(
          xs, hs, WgP + (size_t)l * Dn * Dn, WopB + (size_t)l * Dn * Sn,
          Pg + l * Dn, Qg + l * Dn, bg + l * Dn, bop + l * Dn,
          mean, rstd, xd);
    }
  }

  // after L=4 layers (even), final residual is back in xA
  final_ln_mean<<<dim3(8, Bn), 256, 0, stream>>>(xA, fw, fb, part);
  head_kernel<<<Bn, 256, 0, stream>>>(part, W1, b1, W2, b2, outp);
}